// Round 13
// baseline (161.308 us; speedup 1.0000x reference)
//
#include <hip/hip_runtime.h>
#include <hip/hip_bf16.h>
#include <math.h>

typedef __attribute__((ext_vector_type(8))) short bf16x8;
typedef __attribute__((ext_vector_type(4))) float f32x4;

#define N_B  2
#define CIN  128
#define COUT 128
#define T_   16
#define H_   64
#define W_   64
#define FANIN 3456

// ---- workspace byte offsets ----
#define OFF_WMAX   0          // 128 f32
#define OFF_SMAX   512        // 2 f32
#define OFF_SNORM  1024       // 4096 f32
#define OFF_WSQ    20480      // 16384 f32
#define OFF_DEMOD  86016      // 4096 f32
#define OFF_APACK  102400     // 442368 ushort (884,736 B)  [tap27][c4][m8][lane64][j8]
#define OFF_ZERO   1048576    // 16384 B zero page (below xmt)
#define OFF_XMT    2097152    // 16,777,216 ushort (33.55 MB) [n][t][h][w][cin] bf16
#define ZOFF       (-524288)  // (OFF_ZERO-OFF_XMT)/2 : zero page as ushort offset from xmt

// ---------- prep kernels ----------
__global__ __launch_bounds__(256) void k_zero(uint4* __restrict__ zp) {
    #pragma unroll
    for (int k = 0; k < 4; ++k)
        zp[threadIdx.x + k * 256] = make_uint4(0u, 0u, 0u, 0u);
}

__global__ __launch_bounds__(256) void k_wmax(const float* __restrict__ w,
                                              float* __restrict__ wmax) {
    int o = blockIdx.x;
    const float* p = w + (size_t)o * FANIN;
    float m = 0.f;
    for (int i = threadIdx.x; i < FANIN; i += 256) m = fmaxf(m, fabsf(p[i]));
    __shared__ float red[256];
    red[threadIdx.x] = m; __syncthreads();
    for (int s = 128; s > 0; s >>= 1) {
        if (threadIdx.x < s) red[threadIdx.x] = fmaxf(red[threadIdx.x], red[threadIdx.x + s]);
        __syncthreads();
    }
    if (threadIdx.x == 0) wmax[o] = red[0];
}

__global__ __launch_bounds__(256) void k_smax(const float* __restrict__ s,
                                              float* __restrict__ smax) {
    int n = blockIdx.x;
    const float* p = s + (size_t)n * CIN * T_;
    float m = 0.f;
    for (int i = threadIdx.x; i < CIN * T_; i += 256) m = fmaxf(m, fabsf(p[i]));
    __shared__ float red[256];
    red[threadIdx.x] = m; __syncthreads();
    for (int q = 128; q > 0; q >>= 1) {
        if (threadIdx.x < q) red[threadIdx.x] = fmaxf(red[threadIdx.x], red[threadIdx.x + q]);
        __syncthreads();
    }
    if (threadIdx.x == 0) smax[n] = red[0];
}

__global__ __launch_bounds__(256) void k_snorm(const float* __restrict__ style,
                                               const float* __restrict__ smax,
                                               float* __restrict__ snorm) {
    int idx = blockIdx.x * 256 + threadIdx.x;
    if (idx < N_B * CIN * T_) {
        int n = idx / (CIN * T_);
        snorm[idx] = style[idx] / smax[n];
    }
}

// normalize weight (fp32), pack bf16 into MFMA A-frag order, compute wsq[o][i]
__global__ __launch_bounds__(128) void k_wpack(const float* __restrict__ w,
                                               const float* __restrict__ wmax,
                                               ushort* __restrict__ apack,
                                               float* __restrict__ wsq) {
    int o = blockIdx.x, i = threadIdx.x;
    float inv = 1.0f / (wmax[o] * sqrtf((float)FANIN));
    const float* p = w + ((size_t)o * CIN + i) * 27;
    int c = i >> 5, ii = i & 31;
    int lane = (o & 15) + ((ii >> 3) << 4);   // A: row=l&15, k=(l>>4)*8+j
    int j = ii & 7;
    int m = o >> 4;
    size_t base = (((size_t)c * 8 + m) * 64 + lane) * 8 + j;
    float sq = 0.f;
    #pragma unroll
    for (int tap = 0; tap < 27; tap++) {
        float wn = p[tap] * inv;
        sq = fmaf(wn, wn, sq);
        __hip_bfloat16 hb = __float2bfloat16(wn);
        apack[base + (size_t)tap * 16384] = *(ushort*)&hb;
    }
    wsq[o * CIN + i] = sq;
}

__global__ __launch_bounds__(128) void k_demod(const float* __restrict__ wsq,
                                               const float* __restrict__ snorm,
                                               float* __restrict__ demod) {
    int nt = blockIdx.x;
    int n = nt / T_, t = nt % T_;
    __shared__ float s2[CIN];
    int tid = threadIdx.x;
    float sv = snorm[(n * CIN + tid) * T_ + t];
    s2[tid] = sv * sv;
    __syncthreads();
    const float* wq = wsq + tid * CIN;   // o = tid
    float d = 0.f;
    for (int i = 0; i < CIN; i++) d = fmaf(wq[i], s2[i], d);
    demod[(n * COUT + tid) * T_ + t] = 1.0f / sqrtf(d + 1e-8f);
}

// transpose x -> xmt[n][t][h][w][cin] bf16, style-modulated
__global__ __launch_bounds__(256) void k_xmt(const float* __restrict__ x,
                                             const float* __restrict__ snorm,
                                             ushort* __restrict__ xmt) {
    __shared__ float lds[CIN * 65];
    int bid = blockIdx.x;
    int h = bid & 63, t = (bid >> 6) & 15, n = bid >> 10;
    int tid = threadIdx.x;
    int wl = tid & 63, cq = tid >> 6;
    for (int pass = 0; pass < 32; pass++) {
        int ci = pass * 4 + cq;
        float s = snorm[(n * CIN + ci) * T_ + t];
        float v = x[(((size_t)(n * CIN + ci) * T_ + t) * H_ + h) * W_ + wl] * s;
        lds[ci * 65 + wl] = v;
    }
    __syncthreads();
    int ci2 = tid & 63, wq = tid >> 6;
    uint* dst = (uint*)xmt;
    for (int pass = 0; pass < 16; pass++) {
        int w = pass * 4 + wq;
        float f0 = lds[(2 * ci2) * 65 + w];
        float f1 = lds[(2 * ci2 + 1) * 65 + w];
        __hip_bfloat16 h0 = __float2bfloat16(f0);
        __hip_bfloat16 h1 = __float2bfloat16(f1);
        uint pk = (uint)(*(ushort*)&h0) | ((uint)(*(ushort*)&h1) << 16);
        dst[((((size_t)(n * T_ + t) * H_ + h) * W_ + w)) * 64 + ci2] = pk;
    }
}

// ---------- main MFMA conv ----------
// grid: 512 blocks = n(2)*t(16)*h4(16) -> exactly 2 blocks/CU, no tail.
// block = 256 thr = 4 waves; wave = ONE h-row, FULL 128 Cout x 64 w.
// Per tap: 8 A-frags + 4 ds_read_b128 -> 32 MFMA (B:MFMA = 1:8, halves the
// LDS-read pipe demand vs the 4-mfrag tile — the measured co-bottleneck).
// acc[8][4] = 128 AGPRs; arch regs: A ping-pong 2x8 frags (64) + B 16 +
// goff 19 + addr ~= 119 <= 128 (the no-spill budget established R9-R12).
// Staging: convergent glds (zero regs), zero-page for OOB/pad lanes,
// LDS [q18 (tz3*hh6)][g4][w66] linear in tid, padded 4752->4864 granules.
__global__ __launch_bounds__(256, 2) void k_conv(const ushort* __restrict__ xmt,
                                                 const ushort* __restrict__ apack,
                                                 const float* __restrict__ demod,
                                                 const float* __restrict__ bias,
                                                 float* __restrict__ out) {
    __shared__ ushort __attribute__((aligned(16))) xs[38912];   // 77,824 B

    int bid = blockIdx.x;
    int h4 = bid & 15, t = (bid >> 4) & 15, n = bid >> 8;
    int hbase = h4 * 4;
    int tid = threadIdx.x;
    int lane = tid & 63;
    int hq = tid >> 6;     // wave id = output h row 0..3
    int lw = lane & 15, lg = lane >> 4;

    // ---- chunk-invariant staging source offsets (19 slots, all convergent) ----
    int goff[19];
    #pragma unroll
    for (int k = 0; k < 19; ++k) {
        int idx = tid + (k << 8);
        int off = ZOFF;
        if (idx < 4752) {
            int w = idx % 66;
            int r = idx / 66;
            int g = r & 3;
            int q = r >> 2;            // q = tz*6 + hh, 0..17
            int tz = q / 6, hh = q % 6;
            int gt = t + tz - 1, gh = hbase + hh - 1, gw = w - 1;
            if ((unsigned)gt < T_ && (unsigned)gh < H_ && (unsigned)gw < W_)
                off = (((n * 16 + gt) * 64 + gh) * 64 + gw) * 128 + g * 8;
        }
        goff[k] = off;
    }

#define STAGE(cc) do { \
    _Pragma("unroll") \
    for (int k = 0; k < 19; ++k) \
        __builtin_amdgcn_global_load_lds( \
            (const __attribute__((address_space(1))) void*)(xmt + goff[k] + (cc) * 32), \
            (__attribute__((address_space(3))) void*)((char*)xs + ((size_t)tid + (k << 8)) * 16), \
            16, 0, 0); \
} while (0)

    f32x4 acc[8][4];
    #pragma unroll
    for (int i = 0; i < 8; i++)
        #pragma unroll
        for (int jn = 0; jn < 4; jn++)
            acc[i][jn] = (f32x4){0.f, 0.f, 0.f, 0.f};

    bf16x8 A0[8], A1[8];

#define LOADA(BANK, TAP) do { \
    const ushort* ap_ = apc + (TAP) * 16384; \
    _Pragma("unroll") \
    for (int f_ = 0; f_ < 8; ++f_) \
        BANK[f_] = *(const bf16x8*)(ap_ + f_ * 512); \
} while (0)

// per tap: 4 B granule reads (nb 0..3) feeding 32 MFMA (8 m-frags)
#define TAPC(BANK, TAP) do { \
    const int tz_ = (TAP) / 9, dy_ = ((TAP) / 3) % 3, dx_ = (TAP) % 3; \
    const int q_ = tz_ * 6 + hq + dy_; \
    const ushort* bb_ = &xs[((q_ * 4 + lg) * 66 + lw) * 8 + dx_ * 8]; \
    bf16x8 b0_ = *(const bf16x8*)(bb_); \
    bf16x8 b1_ = *(const bf16x8*)(bb_ + 128); \
    bf16x8 b2_ = *(const bf16x8*)(bb_ + 256); \
    bf16x8 b3_ = *(const bf16x8*)(bb_ + 384); \
    _Pragma("unroll") \
    for (int mi_ = 0; mi_ < 8; ++mi_) { \
        acc[mi_][0] = __builtin_amdgcn_mfma_f32_16x16x32_bf16(BANK[mi_], b0_, acc[mi_][0], 0, 0, 0); \
        acc[mi_][1] = __builtin_amdgcn_mfma_f32_16x16x32_bf16(BANK[mi_], b1_, acc[mi_][1], 0, 0, 0); \
        acc[mi_][2] = __builtin_amdgcn_mfma_f32_16x16x32_bf16(BANK[mi_], b2_, acc[mi_][2], 0, 0, 0); \
        acc[mi_][3] = __builtin_amdgcn_mfma_f32_16x16x32_bf16(BANK[mi_], b3_, acc[mi_][3], 0, 0, 0); \
    } \
} while (0)

#define UNIT(ULD, UCMP, TNEXT, TCUR) \
    LOADA(ULD, TNEXT); __builtin_amdgcn_sched_barrier(0); TAPC(UCMP, TCUR);

    for (int c = 0; c < 4; ++c) {     // cin chunks of 32
        if (c) __syncthreads();       // all waves done reading previous chunk
        STAGE(c);
        __syncthreads();              // vmcnt(0) drained; buffer ready

        const ushort* apc = apack + (c * 4096 + lane * 8);

        LOADA(A0, 0);
        UNIT(A1, A0,  1,  0)  UNIT(A0, A1,  2,  1)  UNIT(A1, A0,  3,  2)
        UNIT(A0, A1,  4,  3)  UNIT(A1, A0,  5,  4)  UNIT(A0, A1,  6,  5)
        UNIT(A1, A0,  7,  6)  UNIT(A0, A1,  8,  7)  UNIT(A1, A0,  9,  8)
        UNIT(A0, A1, 10,  9)  UNIT(A1, A0, 11, 10)  UNIT(A0, A1, 12, 11)
        UNIT(A1, A0, 13, 12)  UNIT(A0, A1, 14, 13)  UNIT(A1, A0, 15, 14)
        UNIT(A0, A1, 16, 15)  UNIT(A1, A0, 17, 16)  UNIT(A0, A1, 18, 17)
        UNIT(A1, A0, 19, 18)  UNIT(A0, A1, 20, 19)  UNIT(A1, A0, 21, 20)
        UNIT(A0, A1, 22, 21)  UNIT(A1, A0, 23, 22)  UNIT(A0, A1, 24, 23)
        UNIT(A1, A0, 25, 24)  UNIT(A0, A1, 26, 25)
        TAPC(A0, 26);
    }
#undef UNIT
#undef LOADA
#undef TAPC
#undef STAGE

    // epilogue: C layout col=lane&15 (w), row=(lane>>4)*4+reg (cout)
    int h = hbase + hq;
    #pragma unroll
    for (int mi = 0; mi < 8; mi++) {
        #pragma unroll
        for (int r = 0; r < 4; r++) {
            int o = mi * 16 + lg * 4 + r;
            float d = demod[(n * COUT + o) * T_ + t];
            float bv = bias[o];
            #pragma unroll
            for (int nb = 0; nb < 4; nb++) {
                float z = fmaf(acc[mi][nb][r], d, bv);
                z = (z >= 0.f ? z : 0.2f * z) * 1.41421356237309515f;
                out[(((size_t)(n * COUT + o) * T_ + t) * H_ + h) * W_ + nb * 16 + lw] = z;
            }
        }
    }
}

extern "C" void kernel_launch(void* const* d_in, const int* in_sizes, int n_in,
                              void* d_out, int out_size, void* d_ws, size_t ws_size,
                              hipStream_t stream) {
    const float* x      = (const float*)d_in[0];
    const float* weight = (const float*)d_in[1];
    const float* style  = (const float*)d_in[2];
    const float* bias   = (const float*)d_in[3];
    float* out = (float*)d_out;

    char* ws = (char*)d_ws;
    float*  wmax  = (float*)(ws + OFF_WMAX);
    float*  smax  = (float*)(ws + OFF_SMAX);
    float*  snorm = (float*)(ws + OFF_SNORM);
    float*  wsq   = (float*)(ws + OFF_WSQ);
    float*  demod = (float*)(ws + OFF_DEMOD);
    uint4*  zpage = (uint4*)(ws + OFF_ZERO);
    ushort* apack = (ushort*)(ws + OFF_APACK);
    ushort* xmt   = (ushort*)(ws + OFF_XMT);

    k_zero <<<1, 256, 0, stream>>>(zpage);
    k_wmax <<<COUT, 256, 0, stream>>>(weight, wmax);
    k_smax <<<N_B, 256, 0, stream>>>(style, smax);
    k_snorm<<<(N_B * CIN * T_ + 255) / 256, 256, 0, stream>>>(style, smax, snorm);
    k_wpack<<<COUT, 128, 0, stream>>>(weight, wmax, apack, wsq);
    k_demod<<<N_B * T_, 128, 0, stream>>>(wsq, snorm, demod);
    k_xmt  <<<N_B * T_ * H_, 256, 0, stream>>>(x, snorm, xmt);

    k_conv<<<N_B * T_ * (H_ / 4), 256, 0, stream>>>(xmt, apack, demod, bias, out);
}

// Round 14
// 139.296 us; speedup vs baseline: 1.1580x; 1.1580x over previous
//
#include <hip/hip_runtime.h>
#include <hip/hip_bf16.h>
#include <math.h>

typedef __attribute__((ext_vector_type(8))) short bf16x8;
typedef __attribute__((ext_vector_type(4))) float f32x4;

#define N_B  2
#define CIN  128
#define COUT 128
#define T_   16
#define H_   64
#define W_   64
#define FANIN 3456

// ---- workspace byte offsets ----
#define OFF_WMAX   0          // 128 f32
#define OFF_SMAX   512        // 2 f32
#define OFF_SNORM  1024       // 4096 f32
#define OFF_WSQ    20480      // 16384 f32
#define OFF_DEMOD  86016      // 4096 f32
#define OFF_APACK  102400     // 442368 ushort (884,736 B)  [tap27][c4][m8][lane64][j8]
#define OFF_ZERO   1048576    // 16384 B zero page (below xmt)
#define OFF_XMT    2097152    // 16,777,216 ushort (33.55 MB) [n][t][h][w][cin] bf16
#define ZOFF       (-524288)  // (OFF_ZERO-OFF_XMT)/2 : zero page as ushort offset from xmt

// ---------- prep kernels ----------
__global__ __launch_bounds__(256) void k_zero(uint4* __restrict__ zp) {
    #pragma unroll
    for (int k = 0; k < 4; ++k)
        zp[threadIdx.x + k * 256] = make_uint4(0u, 0u, 0u, 0u);
}

__global__ __launch_bounds__(256) void k_wmax(const float* __restrict__ w,
                                              float* __restrict__ wmax) {
    int o = blockIdx.x;
    const float* p = w + (size_t)o * FANIN;
    float m = 0.f;
    for (int i = threadIdx.x; i < FANIN; i += 256) m = fmaxf(m, fabsf(p[i]));
    __shared__ float red[256];
    red[threadIdx.x] = m; __syncthreads();
    for (int s = 128; s > 0; s >>= 1) {
        if (threadIdx.x < s) red[threadIdx.x] = fmaxf(red[threadIdx.x], red[threadIdx.x + s]);
        __syncthreads();
    }
    if (threadIdx.x == 0) wmax[o] = red[0];
}

__global__ __launch_bounds__(256) void k_smax(const float* __restrict__ s,
                                              float* __restrict__ smax) {
    int n = blockIdx.x;
    const float* p = s + (size_t)n * CIN * T_;
    float m = 0.f;
    for (int i = threadIdx.x; i < CIN * T_; i += 256) m = fmaxf(m, fabsf(p[i]));
    __shared__ float red[256];
    red[threadIdx.x] = m; __syncthreads();
    for (int q = 128; q > 0; q >>= 1) {
        if (threadIdx.x < q) red[threadIdx.x] = fmaxf(red[threadIdx.x], red[threadIdx.x + q]);
        __syncthreads();
    }
    if (threadIdx.x == 0) smax[n] = red[0];
}

__global__ __launch_bounds__(256) void k_snorm(const float* __restrict__ style,
                                               const float* __restrict__ smax,
                                               float* __restrict__ snorm) {
    int idx = blockIdx.x * 256 + threadIdx.x;
    if (idx < N_B * CIN * T_) {
        int n = idx / (CIN * T_);
        snorm[idx] = style[idx] / smax[n];
    }
}

// normalize weight (fp32), pack bf16 into MFMA A-frag order, compute wsq[o][i]
__global__ __launch_bounds__(128) void k_wpack(const float* __restrict__ w,
                                               const float* __restrict__ wmax,
                                               ushort* __restrict__ apack,
                                               float* __restrict__ wsq) {
    int o = blockIdx.x, i = threadIdx.x;
    float inv = 1.0f / (wmax[o] * sqrtf((float)FANIN));
    const float* p = w + ((size_t)o * CIN + i) * 27;
    int c = i >> 5, ii = i & 31;
    int lane = (o & 15) + ((ii >> 3) << 4);   // A: row=l&15, k=(l>>4)*8+j
    int j = ii & 7;
    int m = o >> 4;
    size_t base = (((size_t)c * 8 + m) * 64 + lane) * 8 + j;
    float sq = 0.f;
    #pragma unroll
    for (int tap = 0; tap < 27; tap++) {
        float wn = p[tap] * inv;
        sq = fmaf(wn, wn, sq);
        __hip_bfloat16 hb = __float2bfloat16(wn);
        apack[base + (size_t)tap * 16384] = *(ushort*)&hb;
    }
    wsq[o * CIN + i] = sq;
}

__global__ __launch_bounds__(128) void k_demod(const float* __restrict__ wsq,
                                               const float* __restrict__ snorm,
                                               float* __restrict__ demod) {
    int nt = blockIdx.x;
    int n = nt / T_, t = nt % T_;
    __shared__ float s2[CIN];
    int tid = threadIdx.x;
    float sv = snorm[(n * CIN + tid) * T_ + t];
    s2[tid] = sv * sv;
    __syncthreads();
    const float* wq = wsq + tid * CIN;   // o = tid
    float d = 0.f;
    for (int i = 0; i < CIN; i++) d = fmaf(wq[i], s2[i], d);
    demod[(n * COUT + tid) * T_ + t] = 1.0f / sqrtf(d + 1e-8f);
}

// transpose x -> xmt[n][t][h][w][cin] bf16, style-modulated
__global__ __launch_bounds__(256) void k_xmt(const float* __restrict__ x,
                                             const float* __restrict__ snorm,
                                             ushort* __restrict__ xmt) {
    __shared__ float lds[CIN * 65];
    int bid = blockIdx.x;
    int h = bid & 63, t = (bid >> 6) & 15, n = bid >> 10;
    int tid = threadIdx.x;
    int wl = tid & 63, cq = tid >> 6;
    for (int pass = 0; pass < 32; pass++) {
        int ci = pass * 4 + cq;
        float s = snorm[(n * CIN + ci) * T_ + t];
        float v = x[(((size_t)(n * CIN + ci) * T_ + t) * H_ + h) * W_ + wl] * s;
        lds[ci * 65 + wl] = v;
    }
    __syncthreads();
    int ci2 = tid & 63, wq = tid >> 6;
    uint* dst = (uint*)xmt;
    for (int pass = 0; pass < 16; pass++) {
        int w = pass * 4 + wq;
        float f0 = lds[(2 * ci2) * 65 + w];
        float f1 = lds[(2 * ci2 + 1) * 65 + w];
        __hip_bfloat16 h0 = __float2bfloat16(f0);
        __hip_bfloat16 h1 = __float2bfloat16(f1);
        uint pk = (uint)(*(ushort*)&h0) | ((uint)(*(ushort*)&h1) << 16);
        dst[((((size_t)(n * T_ + t) * H_ + h) * W_ + w)) * 64 + ci2] = pk;
    }
}

// ---------- main MFMA conv ----------
// grid: 512 blocks = n(2)*t(16)*h4(16) -> 2 blocks/CU, no tail.
// block = 256 thr = 4 waves; wave = ONE h-row, FULL 128 Cout x 64 w.
// Per tap: 8 A-frags + 4 ds_read_b128 -> 32 MFMA (B:MFMA = 1:8).
// acc[8][4] = 128 AGPR. Arch-reg plan (the R13 spill fix): A ping-pong at
// HALF-tap granularity (2 banks x 4 frags = 32 regs, not 64); B held in 16
// regs once per tap, reused by both halves; goff 19; total ~100 <= 128.
// Staging: convergent glds (zero regs), zero-page for OOB/pad lanes,
// LDS [q18 (tz3*hh6)][g4][w66] granules of 16B, padded 4752->4864.
__global__ __launch_bounds__(256, 2) void k_conv(const ushort* __restrict__ xmt,
                                                 const ushort* __restrict__ apack,
                                                 const float* __restrict__ demod,
                                                 const float* __restrict__ bias,
                                                 float* __restrict__ out) {
    __shared__ ushort __attribute__((aligned(16))) xs[38912];   // 77,824 B

    int bid = blockIdx.x;
    int h4 = bid & 15, t = (bid >> 4) & 15, n = bid >> 8;
    int hbase = h4 * 4;
    int tid = threadIdx.x;
    int lane = tid & 63;
    int hq = tid >> 6;     // wave id = output h row 0..3
    int lw = lane & 15, lg = lane >> 4;

    // ---- chunk-invariant staging source offsets (19 slots, all convergent) ----
    int goff[19];
    #pragma unroll
    for (int k = 0; k < 19; ++k) {
        int idx = tid + (k << 8);
        int off = ZOFF;
        if (idx < 4752) {
            int w = idx % 66;
            int r = idx / 66;
            int g = r & 3;
            int q = r >> 2;            // q = tz*6 + hh, 0..17
            int tz = q / 6, hh = q % 6;
            int gt = t + tz - 1, gh = hbase + hh - 1, gw = w - 1;
            if ((unsigned)gt < T_ && (unsigned)gh < H_ && (unsigned)gw < W_)
                off = (((n * 16 + gt) * 64 + gh) * 64 + gw) * 128 + g * 8;
        }
        goff[k] = off;
    }

#define STAGE(cc) do { \
    _Pragma("unroll") \
    for (int k = 0; k < 19; ++k) \
        __builtin_amdgcn_global_load_lds( \
            (const __attribute__((address_space(1))) void*)(xmt + goff[k] + (cc) * 32), \
            (__attribute__((address_space(3))) void*)((char*)xs + ((size_t)tid + (k << 8)) * 16), \
            16, 0, 0); \
} while (0)

    f32x4 acc[8][4];
    #pragma unroll
    for (int i = 0; i < 8; i++)
        #pragma unroll
        for (int jn = 0; jn < 4; jn++)
            acc[i][jn] = (f32x4){0.f, 0.f, 0.f, 0.f};

    bf16x8 A0[4], A1[4];       // half-tap banks: A0 = half0 (Cout 0..63), A1 = half1
    bf16x8 B0, B1, B2, B3;     // per-tap B granules, shared by both halves

#define LOADH(BANK, TAP, HALF) do { \
    const ushort* ap_ = apc + (TAP) * 16384 + (HALF) * 2048; \
    BANK[0] = *(const bf16x8*)(ap_); \
    BANK[1] = *(const bf16x8*)(ap_ + 512); \
    BANK[2] = *(const bf16x8*)(ap_ + 1024); \
    BANK[3] = *(const bf16x8*)(ap_ + 1536); \
} while (0)

#define READB(TAP) do { \
    const int tz_ = (TAP) / 9, dy_ = ((TAP) / 3) % 3, dx_ = (TAP) % 3; \
    const int q_ = tz_ * 6 + hq + dy_; \
    const ushort* bb_ = &xs[((q_ * 4 + lg) * 66 + lw) * 8 + dx_ * 8]; \
    B0 = *(const bf16x8*)(bb_); \
    B1 = *(const bf16x8*)(bb_ + 128); \
    B2 = *(const bf16x8*)(bb_ + 256); \
    B3 = *(const bf16x8*)(bb_ + 384); \
} while (0)

#define MFMAH(BANK, MOFF) do { \
    _Pragma("unroll") \
    for (int mi_ = 0; mi_ < 4; ++mi_) { \
        acc[(MOFF) + mi_][0] = __builtin_amdgcn_mfma_f32_16x16x32_bf16(BANK[mi_], B0, acc[(MOFF) + mi_][0], 0, 0, 0); \
        acc[(MOFF) + mi_][1] = __builtin_amdgcn_mfma_f32_16x16x32_bf16(BANK[mi_], B1, acc[(MOFF) + mi_][1], 0, 0, 0); \
        acc[(MOFF) + mi_][2] = __builtin_amdgcn_mfma_f32_16x16x32_bf16(BANK[mi_], B2, acc[(MOFF) + mi_][2], 0, 0, 0); \
        acc[(MOFF) + mi_][3] = __builtin_amdgcn_mfma_f32_16x16x32_bf16(BANK[mi_], B3, acc[(MOFF) + mi_][3], 0, 0, 0); \
    } \
} while (0)

// per tap: load half1(t), B(t); MFMA half0(t); load half0(t+1); MFMA half1(t)
#define UNIT(TCUR) do { \
    LOADH(A1, TCUR, 1); __builtin_amdgcn_sched_barrier(0); \
    READB(TCUR); MFMAH(A0, 0); \
    LOADH(A0, (TCUR) + 1, 0); __builtin_amdgcn_sched_barrier(0); \
    MFMAH(A1, 4); \
} while (0)

    for (int c = 0; c < 4; ++c) {     // cin chunks of 32
        if (c) __syncthreads();       // all waves done reading previous chunk
        STAGE(c);
        __syncthreads();              // vmcnt(0) drained; buffer ready

        const ushort* apc = apack + (c * 4096 + lane * 8);

        LOADH(A0, 0, 0);
        UNIT(0);  UNIT(1);  UNIT(2);  UNIT(3);  UNIT(4);  UNIT(5);
        UNIT(6);  UNIT(7);  UNIT(8);  UNIT(9);  UNIT(10); UNIT(11);
        UNIT(12); UNIT(13); UNIT(14); UNIT(15); UNIT(16); UNIT(17);
        UNIT(18); UNIT(19); UNIT(20); UNIT(21); UNIT(22); UNIT(23);
        UNIT(24); UNIT(25);
        // last tap: no next-tap prefetch
        LOADH(A1, 26, 1); __builtin_amdgcn_sched_barrier(0);
        READB(26); MFMAH(A0, 0); MFMAH(A1, 4);
    }
#undef UNIT
#undef MFMAH
#undef READB
#undef LOADH
#undef STAGE

    // epilogue: C layout col=lane&15 (w), row=(lane>>4)*4+reg (cout)
    int h = hbase + hq;
    #pragma unroll
    for (int mi = 0; mi < 8; mi++) {
        #pragma unroll
        for (int r = 0; r < 4; r++) {
            int o = mi * 16 + lg * 4 + r;
            float d = demod[(n * COUT + o) * T_ + t];
            float bv = bias[o];
            #pragma unroll
            for (int nb = 0; nb < 4; nb++) {
                float z = fmaf(acc[mi][nb][r], d, bv);
                z = (z >= 0.f ? z : 0.2f * z) * 1.41421356237309515f;
                out[(((size_t)(n * COUT + o) * T_ + t) * H_ + h) * W_ + nb * 16 + lw] = z;
            }
        }
    }
}

extern "C" void kernel_launch(void* const* d_in, const int* in_sizes, int n_in,
                              void* d_out, int out_size, void* d_ws, size_t ws_size,
                              hipStream_t stream) {
    const float* x      = (const float*)d_in[0];
    const float* weight = (const float*)d_in[1];
    const float* style  = (const float*)d_in[2];
    const float* bias   = (const float*)d_in[3];
    float* out = (float*)d_out;

    char* ws = (char*)d_ws;
    float*  wmax  = (float*)(ws + OFF_WMAX);
    float*  smax  = (float*)(ws + OFF_SMAX);
    float*  snorm = (float*)(ws + OFF_SNORM);
    float*  wsq   = (float*)(ws + OFF_WSQ);
    float*  demod = (float*)(ws + OFF_DEMOD);
    uint4*  zpage = (uint4*)(ws + OFF_ZERO);
    ushort* apack = (ushort*)(ws + OFF_APACK);
    ushort* xmt   = (ushort*)(ws + OFF_XMT);

    k_zero <<<1, 256, 0, stream>>>(zpage);
    k_wmax <<<COUT, 256, 0, stream>>>(weight, wmax);
    k_smax <<<N_B, 256, 0, stream>>>(style, smax);
    k_snorm<<<(N_B * CIN * T_ + 255) / 256, 256, 0, stream>>>(style, smax, snorm);
    k_wpack<<<COUT, 128, 0, stream>>>(weight, wmax, apack, wsq);
    k_demod<<<N_B * T_, 128, 0, stream>>>(wsq, snorm, demod);
    k_xmt  <<<N_B * T_ * H_, 256, 0, stream>>>(x, snorm, xmt);

    k_conv<<<N_B * T_ * (H_ / 4), 256, 0, stream>>>(xmt, apack, demod, bias, out);
}

// Round 15
// 138.704 us; speedup vs baseline: 1.1630x; 1.0043x over previous
//
#include <hip/hip_runtime.h>
#include <hip/hip_bf16.h>
#include <math.h>

typedef __attribute__((ext_vector_type(8))) short bf16x8;
typedef __attribute__((ext_vector_type(4))) float f32x4;

#define N_B  2
#define CIN  128
#define COUT 128
#define T_   16
#define H_   64
#define W_   64
#define FANIN 3456

// ---- workspace byte offsets ----
#define OFF_WMAX   0          // 128 f32
#define OFF_SMAX   512        // 2 f32
#define OFF_SNORM  1024       // 4096 f32
#define OFF_WSQ    20480      // 16384 f32
#define OFF_DEMOD  86016      // 4096 f32
#define OFF_APACK  102400     // 442368 ushort (884,736 B)  [tap27][c4][m8][lane64][j8]
#define OFF_ZERO   1048576    // 16384 B zero page (below xmt)
#define OFF_XMT    2097152    // 16,777,216 ushort (33.55 MB) [n][t][h][w][cin] bf16
#define ZOFF       (-524288)  // (OFF_ZERO-OFF_XMT)/2 : zero page as ushort offset from xmt

// ---------- prep kernels ----------
__global__ __launch_bounds__(256) void k_zero(uint4* __restrict__ zp) {
    #pragma unroll
    for (int k = 0; k < 4; ++k)
        zp[threadIdx.x + k * 256] = make_uint4(0u, 0u, 0u, 0u);
}

__global__ __launch_bounds__(256) void k_wmax(const float* __restrict__ w,
                                              float* __restrict__ wmax) {
    int o = blockIdx.x;
    const float* p = w + (size_t)o * FANIN;
    float m = 0.f;
    for (int i = threadIdx.x; i < FANIN; i += 256) m = fmaxf(m, fabsf(p[i]));
    __shared__ float red[256];
    red[threadIdx.x] = m; __syncthreads();
    for (int s = 128; s > 0; s >>= 1) {
        if (threadIdx.x < s) red[threadIdx.x] = fmaxf(red[threadIdx.x], red[threadIdx.x + s]);
        __syncthreads();
    }
    if (threadIdx.x == 0) wmax[o] = red[0];
}

__global__ __launch_bounds__(256) void k_smax(const float* __restrict__ s,
                                              float* __restrict__ smax) {
    int n = blockIdx.x;
    const float* p = s + (size_t)n * CIN * T_;
    float m = 0.f;
    for (int i = threadIdx.x; i < CIN * T_; i += 256) m = fmaxf(m, fabsf(p[i]));
    __shared__ float red[256];
    red[threadIdx.x] = m; __syncthreads();
    for (int q = 128; q > 0; q >>= 1) {
        if (threadIdx.x < q) red[threadIdx.x] = fmaxf(red[threadIdx.x], red[threadIdx.x + q]);
        __syncthreads();
    }
    if (threadIdx.x == 0) smax[n] = red[0];
}

__global__ __launch_bounds__(256) void k_snorm(const float* __restrict__ style,
                                               const float* __restrict__ smax,
                                               float* __restrict__ snorm) {
    int idx = blockIdx.x * 256 + threadIdx.x;
    if (idx < N_B * CIN * T_) {
        int n = idx / (CIN * T_);
        snorm[idx] = style[idx] / smax[n];
    }
}

// normalize weight (fp32), pack bf16 into MFMA A-frag order, compute wsq[o][i]
__global__ __launch_bounds__(128) void k_wpack(const float* __restrict__ w,
                                               const float* __restrict__ wmax,
                                               ushort* __restrict__ apack,
                                               float* __restrict__ wsq) {
    int o = blockIdx.x, i = threadIdx.x;
    float inv = 1.0f / (wmax[o] * sqrtf((float)FANIN));
    const float* p = w + ((size_t)o * CIN + i) * 27;
    int c = i >> 5, ii = i & 31;
    int lane = (o & 15) + ((ii >> 3) << 4);   // A: row=l&15, k=(l>>4)*8+j
    int j = ii & 7;
    int m = o >> 4;
    size_t base = (((size_t)c * 8 + m) * 64 + lane) * 8 + j;
    float sq = 0.f;
    #pragma unroll
    for (int tap = 0; tap < 27; tap++) {
        float wn = p[tap] * inv;
        sq = fmaf(wn, wn, sq);
        __hip_bfloat16 hb = __float2bfloat16(wn);
        apack[base + (size_t)tap * 16384] = *(ushort*)&hb;
    }
    wsq[o * CIN + i] = sq;
}

__global__ __launch_bounds__(128) void k_demod(const float* __restrict__ wsq,
                                               const float* __restrict__ snorm,
                                               float* __restrict__ demod) {
    int nt = blockIdx.x;
    int n = nt / T_, t = nt % T_;
    __shared__ float s2[CIN];
    int tid = threadIdx.x;
    float sv = snorm[(n * CIN + tid) * T_ + t];
    s2[tid] = sv * sv;
    __syncthreads();
    const float* wq = wsq + tid * CIN;   // o = tid
    float d = 0.f;
    for (int i = 0; i < CIN; i++) d = fmaf(wq[i], s2[i], d);
    demod[(n * COUT + tid) * T_ + t] = 1.0f / sqrtf(d + 1e-8f);
}

// transpose x -> xmt[n][t][h][w][cin] bf16, style-modulated
__global__ __launch_bounds__(256) void k_xmt(const float* __restrict__ x,
                                             const float* __restrict__ snorm,
                                             ushort* __restrict__ xmt) {
    __shared__ float lds[CIN * 65];
    int bid = blockIdx.x;
    int h = bid & 63, t = (bid >> 6) & 15, n = bid >> 10;
    int tid = threadIdx.x;
    int wl = tid & 63, cq = tid >> 6;
    for (int pass = 0; pass < 32; pass++) {
        int ci = pass * 4 + cq;
        float s = snorm[(n * CIN + ci) * T_ + t];
        float v = x[(((size_t)(n * CIN + ci) * T_ + t) * H_ + h) * W_ + wl] * s;
        lds[ci * 65 + wl] = v;
    }
    __syncthreads();
    int ci2 = tid & 63, wq = tid >> 6;
    uint* dst = (uint*)xmt;
    for (int pass = 0; pass < 16; pass++) {
        int w = pass * 4 + wq;
        float f0 = lds[(2 * ci2) * 65 + w];
        float f1 = lds[(2 * ci2 + 1) * 65 + w];
        __hip_bfloat16 h0 = __float2bfloat16(f0);
        __hip_bfloat16 h1 = __float2bfloat16(f1);
        uint pk = (uint)(*(ushort*)&h0) | ((uint)(*(ushort*)&h1) << 16);
        dst[((((size_t)(n * T_ + t) * H_ + h) * W_ + w)) * 64 + ci2] = pk;
    }
}

// ---------- main MFMA conv ----------
// grid: 512 blocks = n(2)*t(16)*h4(16) -> 2 blocks/CU, no tail.
// block = 256 thr = 4 waves; wave = ONE h-row, FULL 128 Cout x 64 w.
// Per tap: 8 A-frags + 4 ds_read_b128 -> 32 MFMA (B:MFMA = 1:8).
// acc[8][4] = 128 AGPR. NEW vs R14: B PING-PONG — tap t+1's 4 B granules
// are issued during tap t's MFMAs (155-cyc cover >> ~120-cyc LDS latency),
// removing the per-tap first-use B stall that capped util at ~48%.
// Arch regs: A banks 2x4 frags (32) + B banks 2x16B-granule sets (32) +
// goff 19 + addressing ~30 = ~113 <= 128 (the R9-R13 no-spill law).
// Staging: convergent glds (zero regs), zero-page for OOB/pad lanes,
// LDS [q18 (tz3*hh6)][g4][w66] granules of 16B, padded 4752->4864.
__global__ __launch_bounds__(256, 2) void k_conv(const ushort* __restrict__ xmt,
                                                 const ushort* __restrict__ apack,
                                                 const float* __restrict__ demod,
                                                 const float* __restrict__ bias,
                                                 float* __restrict__ out) {
    __shared__ ushort __attribute__((aligned(16))) xs[38912];   // 77,824 B

    int bid = blockIdx.x;
    int h4 = bid & 15, t = (bid >> 4) & 15, n = bid >> 8;
    int hbase = h4 * 4;
    int tid = threadIdx.x;
    int lane = tid & 63;
    int hq = tid >> 6;     // wave id = output h row 0..3
    int lw = lane & 15, lg = lane >> 4;

    // ---- chunk-invariant staging source offsets (19 slots, all convergent) ----
    int goff[19];
    #pragma unroll
    for (int k = 0; k < 19; ++k) {
        int idx = tid + (k << 8);
        int off = ZOFF;
        if (idx < 4752) {
            int w = idx % 66;
            int r = idx / 66;
            int g = r & 3;
            int q = r >> 2;            // q = tz*6 + hh, 0..17
            int tz = q / 6, hh = q % 6;
            int gt = t + tz - 1, gh = hbase + hh - 1, gw = w - 1;
            if ((unsigned)gt < T_ && (unsigned)gh < H_ && (unsigned)gw < W_)
                off = (((n * 16 + gt) * 64 + gh) * 64 + gw) * 128 + g * 8;
        }
        goff[k] = off;
    }

#define STAGE(cc) do { \
    _Pragma("unroll") \
    for (int k = 0; k < 19; ++k) \
        __builtin_amdgcn_global_load_lds( \
            (const __attribute__((address_space(1))) void*)(xmt + goff[k] + (cc) * 32), \
            (__attribute__((address_space(3))) void*)((char*)xs + ((size_t)tid + (k << 8)) * 16), \
            16, 0, 0); \
} while (0)

    f32x4 acc[8][4];
    #pragma unroll
    for (int i = 0; i < 8; i++)
        #pragma unroll
        for (int jn = 0; jn < 4; jn++)
            acc[i][jn] = (f32x4){0.f, 0.f, 0.f, 0.f};

    bf16x8 A0[4], A1[4];       // half-tap A banks (Cout 0..63 / 64..127)
    bf16x8 Be[4], Bo[4];       // per-tap B banks (even / odd tap)

#define LOADH(BANK, TAP, HALF) do { \
    const ushort* ap_ = apc + (TAP) * 16384 + (HALF) * 2048; \
    BANK[0] = *(const bf16x8*)(ap_); \
    BANK[1] = *(const bf16x8*)(ap_ + 512); \
    BANK[2] = *(const bf16x8*)(ap_ + 1024); \
    BANK[3] = *(const bf16x8*)(ap_ + 1536); \
} while (0)

#define READB(BB, TAP) do { \
    const int tz_ = (TAP) / 9, dy_ = ((TAP) / 3) % 3, dx_ = (TAP) % 3; \
    const int q_ = tz_ * 6 + hq + dy_; \
    const ushort* bb_ = &xs[((q_ * 4 + lg) * 66 + lw) * 8 + dx_ * 8]; \
    BB[0] = *(const bf16x8*)(bb_); \
    BB[1] = *(const bf16x8*)(bb_ + 128); \
    BB[2] = *(const bf16x8*)(bb_ + 256); \
    BB[3] = *(const bf16x8*)(bb_ + 384); \
} while (0)

#define MFMAH(BANK, BB, MOFF) do { \
    _Pragma("unroll") \
    for (int mi_ = 0; mi_ < 4; ++mi_) { \
        acc[(MOFF) + mi_][0] = __builtin_amdgcn_mfma_f32_16x16x32_bf16(BANK[mi_], BB[0], acc[(MOFF) + mi_][0], 0, 0, 0); \
        acc[(MOFF) + mi_][1] = __builtin_amdgcn_mfma_f32_16x16x32_bf16(BANK[mi_], BB[1], acc[(MOFF) + mi_][1], 0, 0, 0); \
        acc[(MOFF) + mi_][2] = __builtin_amdgcn_mfma_f32_16x16x32_bf16(BANK[mi_], BB[2], acc[(MOFF) + mi_][2], 0, 0, 0); \
        acc[(MOFF) + mi_][3] = __builtin_amdgcn_mfma_f32_16x16x32_bf16(BANK[mi_], BB[3], acc[(MOFF) + mi_][3], 0, 0, 0); \
    } \
} while (0)

// tap TCUR: prefetch B(TCUR+1) + A half1(TCUR); MFMA half0 with BCUR;
// prefetch A half0(TCUR+1); MFMA half1 with BCUR.
#define UNIT(BCUR, BNXT, TCUR) do { \
    READB(BNXT, (TCUR) + 1); \
    LOADH(A1, TCUR, 1); \
    __builtin_amdgcn_sched_barrier(0); \
    MFMAH(A0, BCUR, 0); \
    LOADH(A0, (TCUR) + 1, 0); \
    __builtin_amdgcn_sched_barrier(0); \
    MFMAH(A1, BCUR, 4); \
} while (0)

    for (int c = 0; c < 4; ++c) {     // cin chunks of 32
        if (c) __syncthreads();       // all waves done reading previous chunk
        STAGE(c);
        __syncthreads();              // vmcnt(0) drained; buffer ready

        const ushort* apc = apack + (c * 4096 + lane * 8);

        READB(Be, 0);
        LOADH(A0, 0, 0);
        UNIT(Be, Bo,  0);  UNIT(Bo, Be,  1);  UNIT(Be, Bo,  2);
        UNIT(Bo, Be,  3);  UNIT(Be, Bo,  4);  UNIT(Bo, Be,  5);
        UNIT(Be, Bo,  6);  UNIT(Bo, Be,  7);  UNIT(Be, Bo,  8);
        UNIT(Bo, Be,  9);  UNIT(Be, Bo, 10);  UNIT(Bo, Be, 11);
        UNIT(Be, Bo, 12);  UNIT(Bo, Be, 13);  UNIT(Be, Bo, 14);
        UNIT(Bo, Be, 15);  UNIT(Be, Bo, 16);  UNIT(Bo, Be, 17);
        UNIT(Be, Bo, 18);  UNIT(Bo, Be, 19);  UNIT(Be, Bo, 20);
        UNIT(Bo, Be, 21);  UNIT(Be, Bo, 22);  UNIT(Bo, Be, 23);
        UNIT(Be, Bo, 24);  UNIT(Bo, Be, 25);
        // tap 26 (even -> uses Be, already prefetched by UNIT 25)
        LOADH(A1, 26, 1);
        __builtin_amdgcn_sched_barrier(0);
        MFMAH(A0, Be, 0);
        MFMAH(A1, Be, 4);
    }
#undef UNIT
#undef MFMAH
#undef READB
#undef LOADH
#undef STAGE

    // epilogue: C layout col=lane&15 (w), row=(lane>>4)*4+reg (cout)
    int h = hbase + hq;
    #pragma unroll
    for (int mi = 0; mi < 8; mi++) {
        #pragma unroll
        for (int r = 0; r < 4; r++) {
            int o = mi * 16 + lg * 4 + r;
            float d = demod[(n * COUT + o) * T_ + t];
            float bv = bias[o];
            #pragma unroll
            for (int nb = 0; nb < 4; nb++) {
                float z = fmaf(acc[mi][nb][r], d, bv);
                z = (z >= 0.f ? z : 0.2f * z) * 1.41421356237309515f;
                out[(((size_t)(n * COUT + o) * T_ + t) * H_ + h) * W_ + nb * 16 + lw] = z;
            }
        }
    }
}

extern "C" void kernel_launch(void* const* d_in, const int* in_sizes, int n_in,
                              void* d_out, int out_size, void* d_ws, size_t ws_size,
                              hipStream_t stream) {
    const float* x      = (const float*)d_in[0];
    const float* weight = (const float*)d_in[1];
    const float* style  = (const float*)d_in[2];
    const float* bias   = (const float*)d_in[3];
    float* out = (float*)d_out;

    char* ws = (char*)d_ws;
    float*  wmax  = (float*)(ws + OFF_WMAX);
    float*  smax  = (float*)(ws + OFF_SMAX);
    float*  snorm = (float*)(ws + OFF_SNORM);
    float*  wsq   = (float*)(ws + OFF_WSQ);
    float*  demod = (float*)(ws + OFF_DEMOD);
    uint4*  zpage = (uint4*)(ws + OFF_ZERO);
    ushort* apack = (ushort*)(ws + OFF_APACK);
    ushort* xmt   = (ushort*)(ws + OFF_XMT);

    k_zero <<<1, 256, 0, stream>>>(zpage);
    k_wmax <<<COUT, 256, 0, stream>>>(weight, wmax);
    k_smax <<<N_B, 256, 0, stream>>>(style, smax);
    k_snorm<<<(N_B * CIN * T_ + 255) / 256, 256, 0, stream>>>(style, smax, snorm);
    k_wpack<<<COUT, 128, 0, stream>>>(weight, wmax, apack, wsq);
    k_demod<<<N_B * T_, 128, 0, stream>>>(wsq, snorm, demod);
    k_xmt  <<<N_B * T_ * H_, 256, 0, stream>>>(x, snorm, xmt);

    k_conv<<<N_B * T_ * (H_ / 4), 256, 0, stream>>>(xmt, apack, demod, bias, out);
}